// Round 1
// baseline (313.074 us; speedup 1.0000x reference)
//
#include <hip/hip_runtime.h>
#include <math.h>

// FFTConvReservoir: y = tanh(ifft(fft(u)*fft(K)).real + D*u)
// B=8, H=256, L=8192, fp32.
// Kernel 1: FFT each K row (DIF, natural->bitrev), store half-spectrum (k=0..L/2) to ws.
// Kernel 2: real-pair trick: z = u[b0] + i*u[b1]; fwd DIF FFT; Hermitian unpack *Kf repack
//           (bit-reversed addressing); inverse DIT FFT; epilogue skip + tanh.

#define LL 8192
#define LOG2L 13
#define NT 256
#define HH 256
#define KSTRIDE 4160  // padded stride for half-spectrum rows (4097 used)

__device__ __forceinline__ int bitrev13(int x) {
    return (int)(__brev((unsigned)x) >> 19);
}

// Forward radix-2 DIF FFT: natural-order input, bit-reversed output.
// re/im in LDS. Ends with __syncthreads().
__device__ void fft_dif_fwd(float* re, float* im) {
    const int tid = threadIdx.x;
    for (int s = LOG2L - 1; s >= 0; --s) {
        const int half = 1 << s;
        const float ang = -6.2831853071795864f / (float)(half << 1);
        for (int i = tid; i < (LL >> 1); i += NT) {
            const int k = i & (half - 1);
            const int idx0 = ((i >> s) << (s + 1)) | k;
            const int idx1 = idx0 + half;
            const float ar = re[idx0], ai = im[idx0];
            const float br = re[idx1], bi = im[idx1];
            const float sr = ar + br, si = ai + bi;
            const float dr = ar - br, di = ai - bi;
            float sn, c;
            __sincosf(ang * (float)k, &sn, &c);
            re[idx0] = sr; im[idx0] = si;
            re[idx1] = dr * c - di * sn;
            im[idx1] = dr * sn + di * c;
        }
        __syncthreads();
    }
}

// Inverse radix-2 DIT FFT: bit-reversed input, natural-order output, UNNORMALIZED (xN).
// Ends with __syncthreads().
__device__ void fft_dit_inv(float* re, float* im) {
    const int tid = threadIdx.x;
    for (int s = 0; s < LOG2L; ++s) {
        const int half = 1 << s;
        const float ang = 6.2831853071795864f / (float)(half << 1);
        for (int i = tid; i < (LL >> 1); i += NT) {
            const int k = i & (half - 1);
            const int idx0 = ((i >> s) << (s + 1)) | k;
            const int idx1 = idx0 + half;
            float sn, c;
            __sincosf(ang * (float)k, &sn, &c);
            const float ar = re[idx0], ai = im[idx0];
            const float br = re[idx1], bi = im[idx1];
            const float tr = br * c - bi * sn;
            const float ti = br * sn + bi * c;
            re[idx0] = ar + tr; im[idx0] = ai + ti;
            re[idx1] = ar - tr; im[idx1] = ai - ti;
        }
        __syncthreads();
    }
}

__global__ __launch_bounds__(NT) void kfft_kernel(const float* __restrict__ K,
                                                  float2* __restrict__ Kf) {
    __shared__ float re[LL];
    __shared__ float im[LL];
    const int h = blockIdx.x;
    const int tid = threadIdx.x;
    const float4* Kv = (const float4*)(K + (size_t)h * LL);
    #pragma unroll
    for (int t = 0; t < LL / (NT * 4); ++t) {
        const int idx = t * NT + tid;
        const float4 v = Kv[idx];
        const int n = idx * 4;
        re[n] = v.x; re[n + 1] = v.y; re[n + 2] = v.z; re[n + 3] = v.w;
        im[n] = 0.f; im[n + 1] = 0.f; im[n + 2] = 0.f; im[n + 3] = 0.f;
    }
    __syncthreads();
    fft_dif_fwd(re, im);
    // Store half-spectrum k=0..L/2 in natural order (read from bit-reversed LDS pos).
    float2* out = Kf + (size_t)h * KSTRIDE;
    for (int k = tid; k <= LL / 2; k += NT) {
        const int i = bitrev13(k);
        out[k] = make_float2(re[i], im[i]);
    }
}

__global__ __launch_bounds__(NT) void conv_kernel(const float* __restrict__ u,
                                                  const float2* __restrict__ Kf,
                                                  const float* __restrict__ D,
                                                  float* __restrict__ out) {
    __shared__ float re[LL];
    __shared__ float im[LL];
    const int tid = threadIdx.x;
    const int h = blockIdx.x & (HH - 1);
    const int p = blockIdx.x >> 8;          // batch pair 0..3
    const int b0 = p * 2, b1 = b0 + 1;
    const size_t off0 = ((size_t)b0 * HH + h) * LL;
    const size_t off1 = ((size_t)b1 * HH + h) * LL;
    const float4* u0v = (const float4*)(u + off0);
    const float4* u1v = (const float4*)(u + off1);

    #pragma unroll
    for (int t = 0; t < LL / (NT * 4); ++t) {
        const int idx = t * NT + tid;
        const float4 a = u0v[idx];
        const float4 c = u1v[idx];
        const int n = idx * 4;
        re[n] = a.x; re[n + 1] = a.y; re[n + 2] = a.z; re[n + 3] = a.w;
        im[n] = c.x; im[n + 1] = c.y; im[n + 2] = c.z; im[n + 3] = c.w;
    }
    __syncthreads();

    fft_dif_fwd(re, im);   // Z = FFT(u0 + i*u1), bit-reversed in LDS

    // Hermitian unpack -> multiply by Kf -> repack W = Y0 + i*Y1.
    // Each thread owns the unordered pair {k, L-k}; self-pairs at k=0, L/2.
    const float2* kf = Kf + (size_t)h * KSTRIDE;
    for (int k = tid; k <= LL / 2; k += NT) {
        const int i1 = bitrev13(k);
        const int i2 = bitrev13((LL - k) & (LL - 1));
        const float zr1 = re[i1], zi1 = im[i1];
        const float zr2 = re[i2], zi2 = im[i2];
        // U0 = (Z[k] + conj(Z[L-k]))/2 ; U1 = -i(Z[k] - conj(Z[L-k]))/2
        const float u0r = 0.5f * (zr1 + zr2);
        const float u0i = 0.5f * (zi1 - zi2);
        const float u1r = 0.5f * (zi1 + zi2);
        const float u1i = 0.5f * (zr2 - zr1);
        const float2 w = kf[k];
        const float y0r = u0r * w.x - u0i * w.y;
        const float y0i = u0r * w.y + u0i * w.x;
        const float y1r = u1r * w.x - u1i * w.y;
        const float y1i = u1r * w.y + u1i * w.x;
        // W[k] = Y0 + i*Y1
        re[i1] = y0r - y1i;
        im[i1] = y0i + y1r;
        if (k != 0 && k != LL / 2) {
            // W[L-k] = conj(Y0) + i*conj(Y1)
            re[i2] = y0r + y1i;
            im[i2] = y1r - y0i;
        }
    }
    __syncthreads();

    fft_dit_inv(re, im);   // w[n] = L * (y0[n] + i*y1[n]), natural order

    const float dh = D[h];
    const float invN = 1.0f / (float)LL;
    float4* o0 = (float4*)(out + off0);
    float4* o1 = (float4*)(out + off1);
    #pragma unroll
    for (int t = 0; t < LL / (NT * 4); ++t) {
        const int idx = t * NT + tid;
        const float4 a = u0v[idx];
        const float4 c = u1v[idx];
        const int n = idx * 4;
        float4 r0, r1;
        r0.x = tanhf(re[n]     * invN + dh * a.x);
        r0.y = tanhf(re[n + 1] * invN + dh * a.y);
        r0.z = tanhf(re[n + 2] * invN + dh * a.z);
        r0.w = tanhf(re[n + 3] * invN + dh * a.w);
        r1.x = tanhf(im[n]     * invN + dh * c.x);
        r1.y = tanhf(im[n + 1] * invN + dh * c.y);
        r1.z = tanhf(im[n + 2] * invN + dh * c.z);
        r1.w = tanhf(im[n + 3] * invN + dh * c.w);
        o0[idx] = r0;
        o1[idx] = r1;
    }
}

extern "C" void kernel_launch(void* const* d_in, const int* in_sizes, int n_in,
                              void* d_out, int out_size, void* d_ws, size_t ws_size,
                              hipStream_t stream) {
    const float* u = (const float*)d_in[0];   // (8, 256, 8192)
    const float* K = (const float*)d_in[1];   // (256, 8192)
    const float* D = (const float*)d_in[2];   // (256,)
    float* out = (float*)d_out;               // (8, 256, 8192)
    float2* Kf = (float2*)d_ws;               // 256 * KSTRIDE float2 ≈ 8.5 MB

    kfft_kernel<<<dim3(HH), dim3(NT), 0, stream>>>(K, Kf);
    conv_kernel<<<dim3(4 * HH), dim3(NT), 0, stream>>>(u, Kf, D, out);
}

// Round 2
// 226.913 us; speedup vs baseline: 1.3797x; 1.3797x over previous
//
#include <hip/hip_runtime.h>
#include <math.h>

// FFTConvReservoir: y = tanh(ifft(fft(u)*fft(K)).real + D*u); B=8,H=256,L=8192 fp32.
// Round 2: register-resident grouped FFT (passes of 5+4+4 radix-2 stages), 3 LDS
// round-trips instead of 13; XOR bank swizzle makes all pass patterns conflict-free;
// twiddles via 1 sincos + chained cmul/squaring pyramid per group.

#define LL 8192
#define NT 256
#define HH 256
#define KSTRIDE 4160

// Bank swizzle: bijective within each 32-word block; verified conflict-free (2-way)
// for stride-256 (pass A), stride-16 (pass B), contiguous-16 (pass C) patterns.
__device__ __forceinline__ int PHYS(int i) {
    return i ^ ((i >> 5) & 15) ^ (((i >> 8) & 1) << 4);
}
__device__ __forceinline__ int bitrev13(int x) {
    return (int)(__brev((unsigned)x) >> 19);
}
__device__ __forceinline__ float fast_tanh(float x) {
    float e = __expf(2.0f * x);
    return 1.0f - 2.0f / (e + 1.0f);   // x>>0 -> 1, x<<0 -> -1, monotone, ~1e-7 rel err
}

#define TWO_PI 6.2831853071795864f
#define CP16 0.98078528040323f   // cos(pi/16)
#define SP16 0.19509032201613f   // sin(pi/16)
#define CP8  0.92387953251129f   // cos(pi/8)
#define SP8  0.38268343236509f   // sin(pi/8)

// Twiddle pyramid: level j (j=0..JT) lives at offset (1<<j)-1, length 2^j.
// Level JT: exp(i*ang0) * E^m (chained cmul). Level j-1[m] = (level j[m])^2.
template<int JT>
__device__ __forceinline__ void fill_pyr(float ang0, float Er, float Ei,
                                         float* twr, float* twi) {
    float s, c;
    __sincosf(ang0, &s, &c);
    const int off = (1 << JT) - 1;
    twr[off] = c; twi[off] = s;
    #pragma unroll
    for (int m = 1; m < (1 << JT); ++m) {
        const float pr = twr[off + m - 1], pi = twi[off + m - 1];
        twr[off + m] = pr * Er - pi * Ei;
        twi[off + m] = pr * Ei + pi * Er;
    }
    #pragma unroll
    for (int j = JT - 1; j >= 0; --j) {
        #pragma unroll
        for (int m = 0; m < (1 << j); ++m) {
            const float a = twr[(2 << j) - 1 + m], b = twi[(2 << j) - 1 + m];
            twr[(1 << j) - 1 + m] = a * a - b * b;
            twi[(1 << j) - 1 + m] = 2.0f * a * b;
        }
    }
}

// In-register DIF cascade over 2^R2 elements, stages j = R2-1 .. 0.
template<int R2>
__device__ __forceinline__ void dif_apply(float* xr, float* xi,
                                          const float* twr, const float* twi) {
    #pragma unroll
    for (int j = R2 - 1; j >= 0; --j) {
        #pragma unroll
        for (int q = 0; q < (1 << (R2 - 1)); ++q) {
            const int mm = q & ((1 << j) - 1);
            const int m0 = ((q >> j) << (j + 1)) | mm;
            const int m1 = m0 + (1 << j);
            const float wr = twr[(1 << j) - 1 + mm], wi = twi[(1 << j) - 1 + mm];
            const float ar = xr[m0], ai = xi[m0], br = xr[m1], bi = xi[m1];
            xr[m0] = ar + br; xi[m0] = ai + bi;
            const float dr = ar - br, di = ai - bi;
            xr[m1] = dr * wr - di * wi;
            xi[m1] = dr * wi + di * wr;
        }
    }
}

// In-register DIT cascade, stages j = 0 .. R2-1.
template<int R2>
__device__ __forceinline__ void dit_apply(float* xr, float* xi,
                                          const float* twr, const float* twi) {
    #pragma unroll
    for (int j = 0; j < R2; ++j) {
        #pragma unroll
        for (int q = 0; q < (1 << (R2 - 1)); ++q) {
            const int mm = q & ((1 << j) - 1);
            const int m0 = ((q >> j) << (j + 1)) | mm;
            const int m1 = m0 + (1 << j);
            const float wr = twr[(1 << j) - 1 + mm], wi = twi[(1 << j) - 1 + mm];
            const float br = xr[m1] * wr - xi[m1] * wi;
            const float bi = xr[m1] * wi + xi[m1] * wr;
            const float ar = xr[m0], ai = xi[m0];
            xr[m0] = ar + br; xi[m0] = ai + bi;
            xr[m1] = ar - br; xi[m1] = ai - bi;
        }
    }
}

// Forward FFT-8192 (natural -> bit-reversed), equivalent to 13 radix-2 DIF stages
// grouped (12..8)(7..4)(3..0). Ends with __syncthreads().
__device__ void fft_fwd(float* re, float* im, int tid) {
    {   // Group A: stages 12..8, elements p = tid + 256*m
        float xr[32], xi[32], twr[31], twi[31];
        #pragma unroll
        for (int m = 0; m < 32; ++m) {
            const int p = PHYS(tid + (m << 8));
            xr[m] = re[p]; xi[m] = im[p];
        }
        fill_pyr<4>(-(TWO_PI / 8192.0f) * (float)tid, CP16, -SP16, twr, twi);
        dif_apply<5>(xr, xi, twr, twi);
        #pragma unroll
        for (int m = 0; m < 32; ++m) {
            const int p = PHYS(tid + (m << 8));
            re[p] = xr[m]; im[p] = xi[m];
        }
    }
    __syncthreads();
    // Group B: stages 7..4, butterflies g: elements p = 256*(g>>4) + (g&15) + 16*m
    #pragma unroll
    for (int gg = 0; gg < 2; ++gg) {
        const int g = tid + (gg << 8);
        const int base = ((g >> 4) << 8) | (g & 15);
        float xr[16], xi[16], twr[15], twi[15];
        #pragma unroll
        for (int m = 0; m < 16; ++m) {
            const int p = PHYS(base + (m << 4));
            xr[m] = re[p]; xi[m] = im[p];
        }
        fill_pyr<3>(-(TWO_PI / 256.0f) * (float)(g & 15), CP8, -SP8, twr, twi);
        dif_apply<4>(xr, xi, twr, twi);
        #pragma unroll
        for (int m = 0; m < 16; ++m) {
            const int p = PHYS(base + (m << 4));
            re[p] = xr[m]; im[p] = xi[m];
        }
    }
    __syncthreads();
    // Group C: stages 3..0, butterflies i: elements p = 16*i + m (constant twiddles)
    #pragma unroll
    for (int gg = 0; gg < 2; ++gg) {
        const int i0 = tid + (gg << 8);
        const int base = i0 << 4;
        float xr[16], xi[16], twr[15], twi[15];
        #pragma unroll
        for (int m = 0; m < 16; ++m) {
            const int p = PHYS(base + m);
            xr[m] = re[p]; xi[m] = im[p];
        }
        fill_pyr<3>(0.0f, CP8, -SP8, twr, twi);
        dif_apply<4>(xr, xi, twr, twi);
        #pragma unroll
        for (int m = 0; m < 16; ++m) {
            const int p = PHYS(base + m);
            re[p] = xr[m]; im[p] = xi[m];
        }
    }
    __syncthreads();
}

// Inverse FFT-8192 (bit-reversed -> natural), UNNORMALIZED; stages grouped
// (0..3)(4..7)(8..12), twiddles conjugated. Ends with __syncthreads().
__device__ void fft_inv(float* re, float* im, int tid) {
    // Group C': stages 0..3
    #pragma unroll
    for (int gg = 0; gg < 2; ++gg) {
        const int i0 = tid + (gg << 8);
        const int base = i0 << 4;
        float xr[16], xi[16], twr[15], twi[15];
        #pragma unroll
        for (int m = 0; m < 16; ++m) {
            const int p = PHYS(base + m);
            xr[m] = re[p]; xi[m] = im[p];
        }
        fill_pyr<3>(0.0f, CP8, SP8, twr, twi);
        dit_apply<4>(xr, xi, twr, twi);
        #pragma unroll
        for (int m = 0; m < 16; ++m) {
            const int p = PHYS(base + m);
            re[p] = xr[m]; im[p] = xi[m];
        }
    }
    __syncthreads();
    // Group B': stages 4..7
    #pragma unroll
    for (int gg = 0; gg < 2; ++gg) {
        const int g = tid + (gg << 8);
        const int base = ((g >> 4) << 8) | (g & 15);
        float xr[16], xi[16], twr[15], twi[15];
        #pragma unroll
        for (int m = 0; m < 16; ++m) {
            const int p = PHYS(base + (m << 4));
            xr[m] = re[p]; xi[m] = im[p];
        }
        fill_pyr<3>((TWO_PI / 256.0f) * (float)(g & 15), CP8, SP8, twr, twi);
        dit_apply<4>(xr, xi, twr, twi);
        #pragma unroll
        for (int m = 0; m < 16; ++m) {
            const int p = PHYS(base + (m << 4));
            re[p] = xr[m]; im[p] = xi[m];
        }
    }
    __syncthreads();
    {   // Group A': stages 8..12
        float xr[32], xi[32], twr[31], twi[31];
        #pragma unroll
        for (int m = 0; m < 32; ++m) {
            const int p = PHYS(tid + (m << 8));
            xr[m] = re[p]; xi[m] = im[p];
        }
        fill_pyr<4>((TWO_PI / 8192.0f) * (float)tid, CP16, SP16, twr, twi);
        dit_apply<5>(xr, xi, twr, twi);
        #pragma unroll
        for (int m = 0; m < 32; ++m) {
            const int p = PHYS(tid + (m << 8));
            re[p] = xr[m]; im[p] = xi[m];
        }
    }
    __syncthreads();
}

__global__ __launch_bounds__(NT) void kfft_kernel(const float* __restrict__ K,
                                                  float2* __restrict__ Kf) {
    __shared__ float re[LL];
    __shared__ float im[LL];
    const int h = blockIdx.x;
    const int tid = threadIdx.x;
    const float4* Kv = (const float4*)(K + (size_t)h * LL);
    #pragma unroll
    for (int t = 0; t < LL / (NT * 4); ++t) {
        const int idx = t * NT + tid;
        const float4 v = Kv[idx];
        const int n = idx * 4;
        re[PHYS(n)]     = v.x; re[PHYS(n + 1)] = v.y;
        re[PHYS(n + 2)] = v.z; re[PHYS(n + 3)] = v.w;
        im[PHYS(n)]     = 0.f; im[PHYS(n + 1)] = 0.f;
        im[PHYS(n + 2)] = 0.f; im[PHYS(n + 3)] = 0.f;
    }
    __syncthreads();
    fft_fwd(re, im, tid);
    float2* out = Kf + (size_t)h * KSTRIDE;
    for (int k = tid; k <= LL / 2; k += NT) {
        const int i = PHYS(bitrev13(k));
        out[k] = make_float2(re[i], im[i]);
    }
}

__global__ __launch_bounds__(NT) void conv_kernel(const float* __restrict__ u,
                                                  const float2* __restrict__ Kf,
                                                  const float* __restrict__ D,
                                                  float* __restrict__ out) {
    __shared__ float re[LL];
    __shared__ float im[LL];
    const int tid = threadIdx.x;
    const int h = blockIdx.x & (HH - 1);
    const int p = blockIdx.x >> 8;          // batch pair 0..3
    const int b0 = p * 2, b1 = b0 + 1;
    const size_t off0 = ((size_t)b0 * HH + h) * LL;
    const size_t off1 = ((size_t)b1 * HH + h) * LL;
    const float4* u0v = (const float4*)(u + off0);
    const float4* u1v = (const float4*)(u + off1);

    #pragma unroll
    for (int t = 0; t < LL / (NT * 4); ++t) {
        const int idx = t * NT + tid;
        const float4 a = u0v[idx];
        const float4 c = u1v[idx];
        const int n = idx * 4;
        re[PHYS(n)]     = a.x; re[PHYS(n + 1)] = a.y;
        re[PHYS(n + 2)] = a.z; re[PHYS(n + 3)] = a.w;
        im[PHYS(n)]     = c.x; im[PHYS(n + 1)] = c.y;
        im[PHYS(n + 2)] = c.z; im[PHYS(n + 3)] = c.w;
    }
    __syncthreads();

    fft_fwd(re, im, tid);   // Z = FFT(u0 + i*u1), bit-reversed in LDS

    // Hermitian unpack -> multiply by Kf -> repack W = Y0 + i*Y1 (bitrev addressing).
    const float2* kf = Kf + (size_t)h * KSTRIDE;
    for (int k = tid; k <= LL / 2; k += NT) {
        const int i1 = PHYS(bitrev13(k));
        const int i2 = PHYS(bitrev13((LL - k) & (LL - 1)));
        const float zr1 = re[i1], zi1 = im[i1];
        const float zr2 = re[i2], zi2 = im[i2];
        const float u0r = 0.5f * (zr1 + zr2);
        const float u0i = 0.5f * (zi1 - zi2);
        const float u1r = 0.5f * (zi1 + zi2);
        const float u1i = 0.5f * (zr2 - zr1);
        const float2 w = kf[k];
        const float y0r = u0r * w.x - u0i * w.y;
        const float y0i = u0r * w.y + u0i * w.x;
        const float y1r = u1r * w.x - u1i * w.y;
        const float y1i = u1r * w.y + u1i * w.x;
        re[i1] = y0r - y1i;
        im[i1] = y0i + y1r;
        if (k != 0 && k != LL / 2) {
            re[i2] = y0r + y1i;
            im[i2] = y1r - y0i;
        }
    }
    __syncthreads();

    fft_inv(re, im, tid);   // L*(y0 + i*y1), natural order

    const float dh = D[h];
    const float invN = 1.0f / (float)LL;
    float4* o0 = (float4*)(out + off0);
    float4* o1 = (float4*)(out + off1);
    #pragma unroll
    for (int t = 0; t < LL / (NT * 4); ++t) {
        const int idx = t * NT + tid;
        const float4 a = u0v[idx];
        const float4 c = u1v[idx];
        const int n = idx * 4;
        float4 r0, r1;
        r0.x = fast_tanh(re[PHYS(n)]     * invN + dh * a.x);
        r0.y = fast_tanh(re[PHYS(n + 1)] * invN + dh * a.y);
        r0.z = fast_tanh(re[PHYS(n + 2)] * invN + dh * a.z);
        r0.w = fast_tanh(re[PHYS(n + 3)] * invN + dh * a.w);
        r1.x = fast_tanh(im[PHYS(n)]     * invN + dh * c.x);
        r1.y = fast_tanh(im[PHYS(n + 1)] * invN + dh * c.y);
        r1.z = fast_tanh(im[PHYS(n + 2)] * invN + dh * c.z);
        r1.w = fast_tanh(im[PHYS(n + 3)] * invN + dh * c.w);
        o0[idx] = r0;
        o1[idx] = r1;
    }
}

extern "C" void kernel_launch(void* const* d_in, const int* in_sizes, int n_in,
                              void* d_out, int out_size, void* d_ws, size_t ws_size,
                              hipStream_t stream) {
    const float* u = (const float*)d_in[0];   // (8, 256, 8192)
    const float* K = (const float*)d_in[1];   // (256, 8192)
    const float* D = (const float*)d_in[2];   // (256,)
    float* out = (float*)d_out;               // (8, 256, 8192)
    float2* Kf = (float2*)d_ws;               // 256 * KSTRIDE float2 ~ 8.5 MB

    kfft_kernel<<<dim3(HH), dim3(NT), 0, stream>>>(K, Kf);
    conv_kernel<<<dim3(4 * HH), dim3(NT), 0, stream>>>(u, Kf, D, out);
}

// Round 3
// 157.685 us; speedup vs baseline: 1.9854x; 1.4390x over previous
//
#include <hip/hip_runtime.h>
#include <math.h>

// FFTConvReservoir: y = tanh(ifft(fft(u)*fft(K)).real + D*u); B=8,H=256,L=8192 fp32.
// Round 3: (a) complex-pair identity IFFT(FFT(u0+i*u1)*Kf) = conv(u0,K)+i*conv(u1,K)
// removes the Hermitian unpack (the 16-way bank-conflicted pass) entirely — the
// pointwise multiply happens in registers between fwd pass C and inv pass C';
// (b) global loads fused into pass A (scalar coalesced), stores fused into pass A';
// LDS round trips 8 -> 4, barriers 9 -> 4, all LDS patterns 2-way (free) under swizzle.

#define LL 8192
#define NT 256
#define HH 256
#define TWO_PI 6.2831853071795864f
#define CP16 0.98078528040323f   // cos(pi/16)
#define SP16 0.19509032201613f   // sin(pi/16)
#define CP8  0.92387953251129f   // cos(pi/8)
#define SP8  0.38268343236509f   // sin(pi/8)

// Bank swizzle: bijective per 32-word block; all pass patterns are <=2-way (free).
__device__ __forceinline__ int PHYS(int i) {
    return i ^ ((i >> 5) & 15) ^ (((i >> 8) & 1) << 4);
}
__device__ __forceinline__ float fast_tanh(float x) {
    float e = __expf(2.0f * x);
    return 1.0f - 2.0f / (e + 1.0f);
}

// Twiddle pyramid: level j at offset (1<<j)-1, length 2^j. Top level chained cmul
// from (c0,s0) by E; lower levels by squaring.
template<int JT>
__device__ __forceinline__ void fill_pyr_cs(float c0, float s0, float Er, float Ei,
                                            float* twr, float* twi) {
    const int off = (1 << JT) - 1;
    twr[off] = c0; twi[off] = s0;
    #pragma unroll
    for (int m = 1; m < (1 << JT); ++m) {
        const float pr = twr[off + m - 1], pi = twi[off + m - 1];
        twr[off + m] = pr * Er - pi * Ei;
        twi[off + m] = pr * Ei + pi * Er;
    }
    #pragma unroll
    for (int j = JT - 1; j >= 0; --j) {
        #pragma unroll
        for (int m = 0; m < (1 << j); ++m) {
            const float a = twr[(2 << j) - 1 + m], b = twi[(2 << j) - 1 + m];
            twr[(1 << j) - 1 + m] = a * a - b * b;
            twi[(1 << j) - 1 + m] = 2.0f * a * b;
        }
    }
}
template<int JT>
__device__ __forceinline__ void fill_pyr(float ang0, float Er, float Ei,
                                         float* twr, float* twi) {
    float s, c;
    __sincosf(ang0, &s, &c);
    fill_pyr_cs<JT>(c, s, Er, Ei, twr, twi);
}

// In-register DIF cascade over 2^R2 elements, stages j = R2-1 .. 0.
template<int R2>
__device__ __forceinline__ void dif_apply(float* xr, float* xi,
                                          const float* twr, const float* twi) {
    #pragma unroll
    for (int j = R2 - 1; j >= 0; --j) {
        #pragma unroll
        for (int q = 0; q < (1 << (R2 - 1)); ++q) {
            const int mm = q & ((1 << j) - 1);
            const int m0 = ((q >> j) << (j + 1)) | mm;
            const int m1 = m0 + (1 << j);
            const float wr = twr[(1 << j) - 1 + mm], wi = twi[(1 << j) - 1 + mm];
            const float ar = xr[m0], ai = xi[m0], br = xr[m1], bi = xi[m1];
            xr[m0] = ar + br; xi[m0] = ai + bi;
            const float dr = ar - br, di = ai - bi;
            xr[m1] = dr * wr - di * wi;
            xi[m1] = dr * wi + di * wr;
        }
    }
}
// In-register DIT cascade, stages j = 0 .. R2-1.
template<int R2>
__device__ __forceinline__ void dit_apply(float* xr, float* xi,
                                          const float* twr, const float* twi) {
    #pragma unroll
    for (int j = 0; j < R2; ++j) {
        #pragma unroll
        for (int q = 0; q < (1 << (R2 - 1)); ++q) {
            const int mm = q & ((1 << j) - 1);
            const int m0 = ((q >> j) << (j + 1)) | mm;
            const int m1 = m0 + (1 << j);
            const float wr = twr[(1 << j) - 1 + mm], wi = twi[(1 << j) - 1 + mm];
            const float br = xr[m1] * wr - xi[m1] * wi;
            const float bi = xr[m1] * wi + xi[m1] * wr;
            const float ar = xr[m0], ai = xi[m0];
            xr[m0] = ar + br; xi[m0] = ai + bi;
            xr[m1] = ar - br; xi[m1] = ai - bi;
        }
    }
}

// Fwd pass A (stages 12..8): input xr/xi = natural elements [tid + 256m], writes LDS.
__device__ __forceinline__ void fwd_A(float* xr, float* xi, int tid,
                                      float* re, float* im) {
    float twr[31], twi[31];
    fill_pyr<4>(-(TWO_PI / 8192.0f) * (float)tid, CP16, -SP16, twr, twi);
    dif_apply<5>(xr, xi, twr, twi);
    #pragma unroll
    for (int m = 0; m < 32; ++m) {
        const int p = PHYS(tid + (m << 8));
        re[p] = xr[m]; im[p] = xi[m];
    }
}

// Fwd pass B (stages 7..4).
__device__ __forceinline__ void fwd_B(int tid, float* re, float* im) {
    #pragma unroll
    for (int gg = 0; gg < 2; ++gg) {
        const int g = tid + (gg << 8);
        const int base = ((g >> 4) << 8) | (g & 15);
        float xr[16], xi[16], twr[15], twi[15];
        #pragma unroll
        for (int m = 0; m < 16; ++m) {
            const int p = PHYS(base + (m << 4));
            xr[m] = re[p]; xi[m] = im[p];
        }
        fill_pyr<3>(-(TWO_PI / 256.0f) * (float)(g & 15), CP8, -SP8, twr, twi);
        dif_apply<4>(xr, xi, twr, twi);
        #pragma unroll
        for (int m = 0; m < 16; ++m) {
            const int p = PHYS(base + (m << 4));
            re[p] = xr[m]; im[p] = xi[m];
        }
    }
}

// Inv pass B' (stages 4..7, conjugate twiddles).
__device__ __forceinline__ void inv_B(int tid, float* re, float* im) {
    #pragma unroll
    for (int gg = 0; gg < 2; ++gg) {
        const int g = tid + (gg << 8);
        const int base = ((g >> 4) << 8) | (g & 15);
        float xr[16], xi[16], twr[15], twi[15];
        #pragma unroll
        for (int m = 0; m < 16; ++m) {
            const int p = PHYS(base + (m << 4));
            xr[m] = re[p]; xi[m] = im[p];
        }
        fill_pyr<3>((TWO_PI / 256.0f) * (float)(g & 15), CP8, SP8, twr, twi);
        dit_apply<4>(xr, xi, twr, twi);
        #pragma unroll
        for (int m = 0; m < 16; ++m) {
            const int p = PHYS(base + (m << 4));
            re[p] = xr[m]; im[p] = xi[m];
        }
    }
}

__global__ __launch_bounds__(NT) void kfft_kernel(const float* __restrict__ K,
                                                  float2* __restrict__ Kf) {
    __shared__ float re[LL];
    __shared__ float im[LL];
    const int h = blockIdx.x;
    const int tid = threadIdx.x;
    const float* Kr = K + (size_t)h * LL;
    float xr[32], xi[32];
    #pragma unroll
    for (int m = 0; m < 32; ++m) {
        xr[m] = Kr[tid + (m << 8)];
        xi[m] = 0.0f;
    }
    fwd_A(xr, xi, tid, re, im);
    __syncthreads();
    fwd_B(tid, re, im);
    __syncthreads();
    // Plain fwd pass C (stages 3..0, constant twiddles).
    #pragma unroll
    for (int gg = 0; gg < 2; ++gg) {
        const int base = (tid + (gg << 8)) << 4;
        float yr[16], yi[16], twr[15], twi[15];
        #pragma unroll
        for (int m = 0; m < 16; ++m) {
            const int p = PHYS(base + m);
            yr[m] = re[p]; yi[m] = im[p];
        }
        fill_pyr_cs<3>(1.0f, 0.0f, CP8, -SP8, twr, twi);
        dif_apply<4>(yr, yi, twr, twi);
        #pragma unroll
        for (int m = 0; m < 16; ++m) {
            const int p = PHYS(base + m);
            re[p] = yr[m]; im[p] = yi[m];
        }
    }
    __syncthreads();
    // Store spectrum in storage order, laid out [m*512 + i0] to match conv's
    // merged-C register pass (coalesced float2 writes; LDS reads 2-way free).
    float2* outp = Kf + (size_t)h * LL;
    #pragma unroll
    for (int t = 0; t < 32; ++t) {
        const int lin = t * NT + tid;
        const int m = lin >> 9;
        const int i0 = lin & 511;
        const int p = PHYS((i0 << 4) | m);
        outp[lin] = make_float2(re[p], im[p]);
    }
}

__global__ __launch_bounds__(NT) void conv_kernel(const float* __restrict__ u,
                                                  const float2* __restrict__ Kf,
                                                  const float* __restrict__ D,
                                                  float* __restrict__ out) {
    __shared__ float re[LL];
    __shared__ float im[LL];
    const int tid = threadIdx.x;
    const int h = blockIdx.x & (HH - 1);
    const int pr_ = blockIdx.x >> 8;        // batch pair 0..3
    const size_t off0 = ((size_t)(pr_ * 2) * HH + h) * LL;
    const size_t off1 = off0 + (size_t)HH * LL;
    const float* u0 = u + off0;
    const float* u1 = u + off1;

    float xr[32], xi[32];
    #pragma unroll
    for (int m = 0; m < 32; ++m) {
        xr[m] = u0[tid + (m << 8)];   // scalar, lane-consecutive -> coalesced
        xi[m] = u1[tid + (m << 8)];
    }
    fwd_A(xr, xi, tid, re, im);       // z = u0 + i*u1
    __syncthreads();
    fwd_B(tid, re, im);
    __syncthreads();

    // Merged pass C: fwd stages 3..0, pointwise *Kf (storage order), inv stages 0..3.
    const float2* kf = Kf + (size_t)h * LL;
    #pragma unroll
    for (int gg = 0; gg < 2; ++gg) {
        const int i0 = tid + (gg << 8);
        const int base = i0 << 4;
        float yr[16], yi[16], twr[15], twi[15];
        #pragma unroll
        for (int m = 0; m < 16; ++m) {
            const int p = PHYS(base + m);
            yr[m] = re[p]; yi[m] = im[p];
        }
        fill_pyr_cs<3>(1.0f, 0.0f, CP8, -SP8, twr, twi);
        dif_apply<4>(yr, yi, twr, twi);
        #pragma unroll
        for (int m = 0; m < 16; ++m) {
            const float2 w = kf[(m << 9) + i0];   // coalesced float2
            const float a = yr[m], b = yi[m];
            yr[m] = a * w.x - b * w.y;
            yi[m] = a * w.y + b * w.x;
        }
        fill_pyr_cs<3>(1.0f, 0.0f, CP8, SP8, twr, twi);
        dit_apply<4>(yr, yi, twr, twi);
        #pragma unroll
        for (int m = 0; m < 16; ++m) {
            const int p = PHYS(base + m);
            re[p] = yr[m]; im[p] = yi[m];
        }
    }
    __syncthreads();

    inv_B(tid, re, im);
    __syncthreads();

    // Inv pass A' (stages 8..12) into registers; epilogue fused.
    {
        float twr[31], twi[31];
        #pragma unroll
        for (int m = 0; m < 32; ++m) {
            const int p = PHYS(tid + (m << 8));
            xr[m] = re[p]; xi[m] = im[p];
        }
        fill_pyr<4>((TWO_PI / 8192.0f) * (float)tid, CP16, SP16, twr, twi);
        dit_apply<5>(xr, xi, twr, twi);
    }
    // xr[m] = L*y0[tid+256m], xi[m] = L*y1[tid+256m]
    const float dh = D[h];
    const float invN = 1.0f / (float)LL;
    float* o0 = out + off0;
    float* o1 = out + off1;
    #pragma unroll
    for (int m = 0; m < 32; ++m) {
        const int n = tid + (m << 8);
        o0[n] = fast_tanh(xr[m] * invN + dh * u0[n]);
        o1[n] = fast_tanh(xi[m] * invN + dh * u1[n]);
    }
}

extern "C" void kernel_launch(void* const* d_in, const int* in_sizes, int n_in,
                              void* d_out, int out_size, void* d_ws, size_t ws_size,
                              hipStream_t stream) {
    const float* u = (const float*)d_in[0];   // (8, 256, 8192)
    const float* K = (const float*)d_in[1];   // (256, 8192)
    const float* D = (const float*)d_in[2];   // (256,)
    float* out = (float*)d_out;               // (8, 256, 8192)
    float2* Kf = (float2*)d_ws;               // 256 * 8192 float2 = 16 MB

    kfft_kernel<<<dim3(HH), dim3(NT), 0, stream>>>(K, Kf);
    conv_kernel<<<dim3(4 * HH), dim3(NT), 0, stream>>>(u, Kf, D, out);
}